// Round 17
// baseline (656.701 us; speedup 1.0000x reference)
//
#include <hip/hip_runtime.h>
#include <hip/hip_bf16.h>
#include <math.h>

typedef __bf16 bf16_t;
typedef __bf16 bf16x8 __attribute__((ext_vector_type(8)));
typedef __bf16 bf16x4 __attribute__((ext_vector_type(4)));
typedef float  f32x4  __attribute__((ext_vector_type(4)));

enum { EPI_BF16_BIAS = 0, EPI_F32_SCALE = 1, EPI_BF16 = 2, EPI_F32_BIAS_RES = 3, EPI_BF16_BIAS_GELU = 4 };

__device__ __forceinline__ float gelu_exact(float v) {
  return 0.5f * v * (1.0f + erff(v * 0.7071067811865476f));
}

__device__ __forceinline__ void gld_lds16(const bf16_t* g, bf16_t* l) {
  __builtin_amdgcn_global_load_lds(
      (const __attribute__((address_space(1))) uint32_t*)(uintptr_t)g,
      (__attribute__((address_space(3))) uint32_t*)(uintptr_t)l, 16, 0, 0);
}

#define SB()    __builtin_amdgcn_s_barrier()
#define SCHED() __builtin_amdgcn_sched_barrier(0)
#define VMW0()  asm volatile("s_waitcnt vmcnt(0)" ::: "memory")
#define VMW(N)  asm volatile("s_waitcnt vmcnt(" #N ")" ::: "memory")
#define LGKM0() do { asm volatile("s_waitcnt lgkmcnt(0)" ::: "memory"); __builtin_amdgcn_sched_barrier(0); } while(0)

// swizzled LDS read: 16B frag at (rowbase+lr, k-slot (ks*4+lg) XOR (lr&7)); rows 64 elems
#define RD(base, rowbase, kslot) \
  (*(const bf16x8*)((base) + ((rowbase) + lr) * 64 + (((((kslot) << 2) | lg)) ^ (lr & 7)) * 8))

// ---------------- GEMM (champion): 256x256 tile, BK=64, 8 waves, 2-phase counted loop ----
template<int EPI, int ZDIV>
__global__ __launch_bounds__(512, 2) void tb_gemm8(
    const bf16_t* __restrict__ A, int lda, long long strideA, long long kofA,
    const bf16_t* __restrict__ B, int ldb, long long strideB, long long kofB,
    const float* __restrict__ bias,
    const float* __restrict__ resid,
    void* __restrict__ Cp, int ldc, long long strideC,
    int K, float scale)
{
  __shared__ __align__(16) bf16_t sm[65536];  // 128 KiB: 2 bufs x (A 16384 + B 16384)

  const int tid = threadIdx.x;
  const int lane = tid & 63;
  const int wid = tid >> 6;
  const int wm = wid >> 2;   // 0..1
  const int wn = wid & 3;    // 0..3
  const int lr = lane & 15;
  const int lg = lane >> 4;
  const int z = blockIdx.z;
  const int batch = z / ZDIV;
  const int ks = z % ZDIV;
  const int m0 = blockIdx.y * 256;
  const int n0 = blockIdx.x * 256;

  const bf16_t* Ag = A + (size_t)batch * strideA + (size_t)ks * kofA + (size_t)m0 * lda;
  const bf16_t* Bg = B + (size_t)batch * strideB + (size_t)ks * kofB + (size_t)n0 * ldb;

  const int l3 = lane >> 3;                 // row-within-chunk
  const int sl8 = ((lane & 7) ^ l3) << 3;   // inverse-swizzled source col (elems)

  f32x4 acc[8][4];
#pragma unroll
  for (int i = 0; i < 8; ++i)
#pragma unroll
    for (int j = 0; j < 4; ++j) acc[i][j] = (f32x4){0.f, 0.f, 0.f, 0.f};

  auto stage = [&](int par, int kt) {
    bf16_t* da = sm + (par << 15);
    bf16_t* db = da + 16384;
#pragma unroll
    for (int h = 0; h < 2; ++h)
#pragma unroll
      for (int q = 0; q < 2; ++q) {
        int c = (wid << 1) + q;                 // chunk 0..15
        int row = (h << 7) + (c << 3) + l3;
        gld_lds16(Ag + (size_t)row * lda + kt + sl8, da + (h << 13) + (c << 9) + lane * 8);
        gld_lds16(Bg + (size_t)row * ldb + kt + sl8, db + (h << 13) + (c << 9) + lane * 8);
      }
  };

  const int NT = K >> 6;
  stage(0, 0);
  VMW0();
  SB();

  for (int t = 0; t < NT; ++t) {
    SCHED();
    const bf16_t* cura = sm + ((t & 1) << 15);
    const bf16_t* curb = cura + 16384;
    if (t + 1 < NT) stage((t + 1) & 1, (t + 1) << 6);

    bf16x8 bF[4][2], aF[4][2];
#pragma unroll
    for (int jj = 0; jj < 4; ++jj) {
      bF[jj][0] = RD(curb, jj * 64 + wn * 16, 0);
      bF[jj][1] = RD(curb, jj * 64 + wn * 16, 1);
    }
#pragma unroll
    for (int ii = 0; ii < 4; ++ii) {
      aF[ii][0] = RD(cura, ii * 32 + wm * 16, 0);
      aF[ii][1] = RD(cura, ii * 32 + wm * 16, 1);
    }
    __builtin_amdgcn_s_setprio(1);
#pragma unroll
    for (int ii = 0; ii < 4; ++ii)
#pragma unroll
      for (int jj = 0; jj < 4; ++jj)
#pragma unroll
        for (int kk = 0; kk < 2; ++kk)
          acc[ii][jj] = __builtin_amdgcn_mfma_f32_16x16x32_bf16(aF[ii][kk], bF[jj][kk], acc[ii][jj], 0, 0, 0);
    __builtin_amdgcn_s_setprio(0);
#pragma unroll
    for (int ii = 0; ii < 4; ++ii) {
      aF[ii][0] = RD(cura, 128 + ii * 32 + wm * 16, 0);
      aF[ii][1] = RD(cura, 128 + ii * 32 + wm * 16, 1);
    }
    __builtin_amdgcn_s_setprio(1);
#pragma unroll
    for (int ii = 0; ii < 4; ++ii)
#pragma unroll
      for (int jj = 0; jj < 4; ++jj)
#pragma unroll
        for (int kk = 0; kk < 2; ++kk)
          acc[4 + ii][jj] = __builtin_amdgcn_mfma_f32_16x16x32_bf16(aF[ii][kk], bF[jj][kk], acc[4 + ii][jj], 0, 0, 0);
    __builtin_amdgcn_s_setprio(0);

    SCHED();
    if (t + 1 < NT) {
      VMW0();
      SB();
    }
  }

  // ---- epilogue ----
#pragma unroll
  for (int i = 0; i < 8; ++i) {
    const int mr = ((i >> 2) << 7) + ((i & 3) << 5) + (wm << 4);
#pragma unroll
    for (int j = 0; j < 4; ++j) {
      const int nc = j * 64 + (wn << 4);
#pragma unroll
      for (int r = 0; r < 4; ++r) {
        int row = m0 + mr + lg * 4 + r;
        int col = n0 + nc + lr;
        float v = acc[i][j][r] * scale;
        if constexpr (EPI == EPI_BF16_BIAS || EPI == EPI_F32_BIAS_RES || EPI == EPI_BF16_BIAS_GELU)
          v += bias[col];
        if constexpr (EPI == EPI_BF16_BIAS_GELU)
          v = gelu_exact(v);
        if constexpr (EPI == EPI_F32_BIAS_RES)
          v += resid[(size_t)row * ldc + col];
        if constexpr (EPI == EPI_BF16_BIAS || EPI == EPI_BF16 || EPI == EPI_BF16_BIAS_GELU) {
          ((bf16_t*)Cp)[(size_t)z * strideC + (size_t)row * ldc + col] = (bf16_t)v;
        } else {
          ((float*)Cp)[(size_t)z * strideC + (size_t)row * ldc + col] = v;
        }
      }
    }
  }
}

// ---------------- GEMM (experimental): 8-phase uniform-stage counted-vmcnt loop ----
// Full-line LDS rows (128 B), champion swizzle pair. Snake quadrants:
// ph1 (mh0,nh0): 12 ds_read; stage A-h0(t+1)->oth; lgkm(8)
// ph2 (mh1,nh0):  8 ds_read (B reused); stage B-h1(t+1)->oth
// ph3 (mh1,nh1):  4 ds_read (A reused); stage B-h0(t+2)->cur  [B-h0(t) last read ph1]
// ph4 (mh0,nh1):  8 ds_read (B reused); stage A-h1(t+2)->cur  [A-h1(t) last read ph2]
//                 + vmcnt(4) [FIFO: retires exactly tile t+1's 8 loads; 4 in flight]
// Requires NT >= 2.
template<int EPI, int ZDIV>
__global__ __launch_bounds__(512, 2) void tb_gemm8p(
    const bf16_t* __restrict__ A, int lda, long long strideA, long long kofA,
    const bf16_t* __restrict__ B, int ldb, long long strideB, long long kofB,
    const float* __restrict__ bias,
    const float* __restrict__ resid,
    void* __restrict__ Cp, int ldc, long long strideC,
    int K, float scale)
{
  __shared__ __align__(16) bf16_t sm[65536];  // 2 bufs x (A 16384 + B 16384)

  const int tid = threadIdx.x;
  const int lane = tid & 63;
  const int wid = tid >> 6;
  const int wm = wid >> 2;
  const int wn = wid & 3;
  const int lr = lane & 15;
  const int lg = lane >> 4;
  const int z = blockIdx.z;
  const int batch = z / ZDIV;
  const int ks = z % ZDIV;
  const int m0 = blockIdx.y * 256;
  const int n0 = blockIdx.x * 256;

  const bf16_t* Ag = A + (size_t)batch * strideA + (size_t)ks * kofA + (size_t)m0 * lda;
  const bf16_t* Bg = B + (size_t)batch * strideB + (size_t)ks * kofB + (size_t)n0 * ldb;

  const int l3 = lane >> 3;
  const int sl8 = ((lane & 7) ^ l3) << 3;

  f32x4 acc[8][4];
#pragma unroll
  for (int i = 0; i < 8; ++i)
#pragma unroll
    for (int j = 0; j < 4; ++j) acc[i][j] = (f32x4){0.f, 0.f, 0.f, 0.f};

  // stage one 128-row half of one matrix (moff 0 = A, 16384 = B): 2 gload_lds/wave
  auto stageU = [&](bf16_t* buf, int moff, const bf16_t* G, int ld, int h, int kt) {
#pragma unroll
    for (int q = 0; q < 2; ++q) {
      int c = (wid << 1) + q;
      int row = (h << 7) + (c << 3) + l3;
      gld_lds16(G + (size_t)row * ld + kt + sl8, buf + moff + (h << 13) + (c << 9) + lane * 8);
    }
  };

#define MFMA_Q(IB, JB) do { \
  __builtin_amdgcn_s_setprio(1); \
  _Pragma("unroll") for (int ii = 0; ii < 4; ++ii) \
  _Pragma("unroll") for (int jj = 0; jj < 2; ++jj) \
  _Pragma("unroll") for (int kk = 0; kk < 2; ++kk) \
    acc[(IB)+ii][(JB)+jj] = __builtin_amdgcn_mfma_f32_16x16x32_bf16( \
        aF[ii][kk], bF[jj][kk], acc[(IB)+ii][(JB)+jj], 0, 0, 0); \
  __builtin_amdgcn_s_setprio(0); } while (0)

  const int NT = K >> 6;
  bf16_t* buf0 = sm;
  bf16_t* buf1 = sm + 32768;

  // prologue: tile0 x4 + B-h0(1) + A-h1(1) = 12 loads; vmcnt(4) retires tile0's 8
  stageU(buf0, 0,     Ag, lda, 0, 0);
  stageU(buf0, 16384, Bg, ldb, 0, 0);
  stageU(buf0, 16384, Bg, ldb, 1, 0);
  stageU(buf0, 0,     Ag, lda, 1, 0);
  stageU(buf1, 16384, Bg, ldb, 0, 64);
  stageU(buf1, 0,     Ag, lda, 1, 64);
  VMW(4);
  SB();

  bf16x8 aF[4][2], bF[2][2];

  for (int t = 0; t < NT; ++t) {
    bf16_t* cur = sm + ((t & 1) << 15);
    bf16_t* oth = sm + (((t + 1) & 1) << 15);
    const bf16_t* curb = cur + 16384;
    const int kt1 = (t + 1) << 6;
    const int kt2 = (t + 2) << 6;

    // ---- ph1: (mh0, nh0) ----
#pragma unroll
    for (int ii = 0; ii < 4; ++ii) {
      aF[ii][0] = RD(cur, ii * 32 + wm * 16, 0);
      aF[ii][1] = RD(cur, ii * 32 + wm * 16, 1);
    }
#pragma unroll
    for (int jj = 0; jj < 2; ++jj) {
      bF[jj][0] = RD(curb, jj * 64 + wn * 16, 0);
      bF[jj][1] = RD(curb, jj * 64 + wn * 16, 1);
    }
    if (t + 1 < NT) stageU(oth, 0, Ag, lda, 0, kt1);        // A-h0(t+1)
    asm volatile("s_waitcnt lgkmcnt(8)" ::: "memory");
    SB(); LGKM0();
    MFMA_Q(0, 0);
    SB();

    // ---- ph2: (mh1, nh0) ----
#pragma unroll
    for (int ii = 0; ii < 4; ++ii) {
      aF[ii][0] = RD(cur, 128 + ii * 32 + wm * 16, 0);
      aF[ii][1] = RD(cur, 128 + ii * 32 + wm * 16, 1);
    }
    if (t + 1 < NT) stageU(oth, 16384, Bg, ldb, 1, kt1);    // B-h1(t+1)
    SB(); LGKM0();
    MFMA_Q(4, 0);
    SB();

    // ---- ph3: (mh1, nh1) ----
#pragma unroll
    for (int jj = 0; jj < 2; ++jj) {
      bF[jj][0] = RD(curb, 128 + jj * 64 + wn * 16, 0);
      bF[jj][1] = RD(curb, 128 + jj * 64 + wn * 16, 1);
    }
    if (t + 2 < NT) stageU(cur, 16384, Bg, ldb, 0, kt2);    // B-h0(t+2) into cur
    SB(); LGKM0();
    MFMA_Q(4, 2);
    SB();

    // ---- ph4: (mh0, nh1) ----
#pragma unroll
    for (int ii = 0; ii < 4; ++ii) {
      aF[ii][0] = RD(cur, ii * 32 + wm * 16, 0);
      aF[ii][1] = RD(cur, ii * 32 + wm * 16, 1);
    }
    if (t + 2 < NT) {
      stageU(cur, 0, Ag, lda, 1, kt2);                      // A-h1(t+2) into cur
      VMW(4);                                               // tile t+1 fully landed
    } else if (t + 1 < NT) {
      VMW(0);                                               // tail: drain for last tile
    }
    SB(); LGKM0();
    MFMA_Q(0, 2);
    SB();
  }
#undef MFMA_Q

  // ---- epilogue (same mapping as champion) ----
#pragma unroll
  for (int i = 0; i < 8; ++i) {
    const int mr = ((i >> 2) << 7) + ((i & 3) << 5) + (wm << 4);
#pragma unroll
    for (int j = 0; j < 4; ++j) {
      const int nc = j * 64 + (wn << 4);
#pragma unroll
      for (int r = 0; r < 4; ++r) {
        int row = m0 + mr + lg * 4 + r;
        int col = n0 + nc + lr;
        float v = acc[i][j][r] * scale;
        if constexpr (EPI == EPI_BF16_BIAS || EPI == EPI_F32_BIAS_RES || EPI == EPI_BF16_BIAS_GELU)
          v += bias[col];
        if constexpr (EPI == EPI_BF16_BIAS_GELU)
          v = gelu_exact(v);
        if constexpr (EPI == EPI_F32_BIAS_RES)
          v += resid[(size_t)row * ldc + col];
        if constexpr (EPI == EPI_BF16_BIAS || EPI == EPI_BF16 || EPI == EPI_BF16_BIAS_GELU) {
          ((bf16_t*)Cp)[(size_t)z * strideC + (size_t)row * ldc + col] = (bf16_t)v;
        } else {
          ((float*)Cp)[(size_t)z * strideC + (size_t)row * ldc + col] = v;
        }
      }
    }
  }
}

// ---------------- fused prep: 4 weight transposes (f32->bf16 [N][K]) + LN1 ----------------
__device__ __forceinline__ void prep_transpose(
    const float* __restrict__ in, bf16_t* __restrict__ outT, int R, int C,
    int tile_id, float (*tile)[33], int t)
{
  int tx = tile_id % (C / 32);
  int ty = tile_id / (C / 32);
  int c0 = tx * 32;
  int r0 = ty * 32;
  int r = t >> 3;
  int c4 = (t & 7) * 4;
  float4 d = *(const float4*)(in + (size_t)(r0 + r) * C + c0 + c4);
  tile[r][c4 + 0] = d.x; tile[r][c4 + 1] = d.y; tile[r][c4 + 2] = d.z; tile[r][c4 + 3] = d.w;
  __syncthreads();
  int c = t >> 3;
  int r4 = (t & 7) * 4;
  bf16x4 o;
  o[0] = (bf16_t)tile[r4 + 0][c];
  o[1] = (bf16_t)tile[r4 + 1][c];
  o[2] = (bf16_t)tile[r4 + 2][c];
  o[3] = (bf16_t)tile[r4 + 3][c];
  *(bf16x4*)(outT + (size_t)(c0 + c) * R + r0 + r4) = o;
}

__global__ __launch_bounds__(256) void tb_prep(
    const float* __restrict__ x, const float* __restrict__ g, const float* __restrict__ b,
    bf16_t* __restrict__ h,
    const float* __restrict__ qkv_w, bf16_t* __restrict__ qkv_wT,
    const float* __restrict__ out_w, bf16_t* __restrict__ out_wT,
    const float* __restrict__ w1, bf16_t* __restrict__ w1T,
    const float* __restrict__ w2, bf16_t* __restrict__ w2T)
{
  __shared__ float tile[32][33];
  __shared__ float sa[4], sb[4];
  int bid = blockIdx.x;
  int t = threadIdx.x;
  if (bid < 12288) {
    prep_transpose(qkv_w, qkv_wT, 2048, 6144, bid, tile, t);
  } else if (bid < 16384) {
    prep_transpose(out_w, out_wT, 2048, 2048, bid - 12288, tile, t);
  } else if (bid < 32768) {
    prep_transpose(w1, w1T, 2048, 8192, bid - 16384, tile, t);
  } else if (bid < 49152) {
    prep_transpose(w2, w2T, 8192, 2048, bid - 32768, tile, t);
  } else {
    int row = bid - 49152;
    const float* xr = x + (size_t)row * 2048;
    float4 v0 = *(const float4*)(xr + t * 8);
    float4 v1 = *(const float4*)(xr + t * 8 + 4);
    float a[8] = {v0.x, v0.y, v0.z, v0.w, v1.x, v1.y, v1.z, v1.w};
    float s = 0.f, q = 0.f;
#pragma unroll
    for (int j = 0; j < 8; ++j) { s += a[j]; q += a[j] * a[j]; }
#pragma unroll
    for (int o = 32; o; o >>= 1) { s += __shfl_down(s, o); q += __shfl_down(q, o); }
    int w = t >> 6, l = t & 63;
    if (l == 0) { sa[w] = s; sb[w] = q; }
    __syncthreads();
    if (t == 0) {
      sa[0] = sa[0] + sa[1] + sa[2] + sa[3];
      sb[0] = sb[0] + sb[1] + sb[2] + sb[3];
    }
    __syncthreads();
    float mu = sa[0] * (1.0f / 2048.0f);
    float var = sb[0] * (1.0f / 2048.0f) - mu * mu;
    float rs = rsqrtf(var + 1e-5f);
    float4 g0 = *(const float4*)(g + t * 8);
    float4 g1 = *(const float4*)(g + t * 8 + 4);
    float4 b0 = *(const float4*)(b + t * 8);
    float4 b1 = *(const float4*)(b + t * 8 + 4);
    float gv[8] = {g0.x, g0.y, g0.z, g0.w, g1.x, g1.y, g1.z, g1.w};
    float bv[8] = {b0.x, b0.y, b0.z, b0.w, b1.x, b1.y, b1.z, b1.w};
    bf16x8 o8;
#pragma unroll
    for (int j = 0; j < 8; ++j) o8[j] = (bf16_t)((a[j] - mu) * rs * gv[j] + bv[j]);
    *(bf16x8*)(h + (size_t)row * 2048 + t * 8) = o8;
  }
}

// ---------------- final combine: out = x2 + p0 + p1 + bias (p bf16, x2/out f32) ----
__global__ __launch_bounds__(256) void tb_combine_f(
    const float* __restrict__ x2, const bf16_t* __restrict__ p,
    const float* __restrict__ bias, float* __restrict__ out)
{
  size_t o = ((size_t)blockIdx.x * 256 + threadIdx.x) * 8;
  float4 a0 = *(const float4*)(x2 + o);
  float4 a1 = *(const float4*)(x2 + o + 4);
  bf16x8 pa = *(const bf16x8*)(p + o);
  bf16x8 pb = *(const bf16x8*)(p + 8388608 + o);
  size_t c = o & 2047;
  float4 b0 = *(const float4*)(bias + c);
  float4 b1 = *(const float4*)(bias + c + 4);
  float4 r0, r1;
  r0.x = a0.x + (float)pa[0] + (float)pb[0] + b0.x;
  r0.y = a0.y + (float)pa[1] + (float)pb[1] + b0.y;
  r0.z = a0.z + (float)pa[2] + (float)pb[2] + b0.z;
  r0.w = a0.w + (float)pa[3] + (float)pb[3] + b0.w;
  r1.x = a1.x + (float)pa[4] + (float)pb[4] + b1.x;
  r1.y = a1.y + (float)pa[5] + (float)pb[5] + b1.y;
  r1.z = a1.z + (float)pa[6] + (float)pb[6] + b1.z;
  r1.w = a1.w + (float)pa[7] + (float)pb[7] + b1.w;
  *(float4*)(out + o) = r0;
  *(float4*)(out + o + 4) = r1;
}

// ---------------- PV combine: ao = bf16(p[2b] + p[2b+1]), p bf16 [4][2048][2048] ----
__global__ __launch_bounds__(256) void tb_combine_pv(
    const bf16_t* __restrict__ p, bf16_t* __restrict__ ao)
{
  size_t o = ((size_t)blockIdx.x * 256 + threadIdx.x) * 8;
  size_t b = o >> 22;
  size_t w = o & 4194303;
  const bf16_t* p0 = p + (b << 1) * 4194304 + w;
  const bf16_t* p1 = p0 + 4194304;
  bf16x8 a = *(const bf16x8*)p0;
  bf16x8 c = *(const bf16x8*)p1;
  bf16x8 r;
#pragma unroll
  for (int j = 0; j < 8; ++j) r[j] = (bf16_t)((float)a[j] + (float)c[j]);
  *(bf16x8*)(ao + o) = r;
}

// ---------------- fused outproj-combine + LayerNorm2 ----------------
__global__ __launch_bounds__(256) void tb_combine_ln(
    const float* __restrict__ x, const bf16_t* __restrict__ p,
    const float* __restrict__ ob,
    const float* __restrict__ g, const float* __restrict__ b,
    float* __restrict__ x2, bf16_t* __restrict__ h)
{
  __shared__ float sa[4], sb[4];
  int row = blockIdx.x;
  int t = threadIdx.x;
  const float* xr = x + (size_t)row * 2048;
  const bf16_t* p0 = p + (size_t)row * 2048;
  const bf16_t* p1 = p0 + 8388608;
  float4 v0 = *(const float4*)(xr + t * 8);
  float4 v1 = *(const float4*)(xr + t * 8 + 4);
  bf16x8 pa = *(const bf16x8*)(p0 + t * 8);
  bf16x8 pb = *(const bf16x8*)(p1 + t * 8);
  float4 o0 = *(const float4*)(ob + t * 8);
  float4 o1 = *(const float4*)(ob + t * 8 + 4);
  float a[8] = {v0.x, v0.y, v0.z, v0.w, v1.x, v1.y, v1.z, v1.w};
  float ov[8] = {o0.x, o0.y, o0.z, o0.w, o1.x, o1.y, o1.z, o1.w};
  float s = 0.f, q = 0.f;
#pragma unroll
  for (int j = 0; j < 8; ++j) {
    a[j] += (float)pa[j] + (float)pb[j] + ov[j];
    s += a[j]; q += a[j] * a[j];
  }
  float4 w0 = {a[0], a[1], a[2], a[3]};
  float4 w1 = {a[4], a[5], a[6], a[7]};
  *(float4*)(x2 + (size_t)row * 2048 + t * 8) = w0;
  *(float4*)(x2 + (size_t)row * 2048 + t * 8 + 4) = w1;
#pragma unroll
  for (int o = 32; o; o >>= 1) { s += __shfl_down(s, o); q += __shfl_down(q, o); }
  int w = t >> 6, l = t & 63;
  if (l == 0) { sa[w] = s; sb[w] = q; }
  __syncthreads();
  if (t == 0) {
    sa[0] = sa[0] + sa[1] + sa[2] + sa[3];
    sb[0] = sb[0] + sb[1] + sb[2] + sb[3];
  }
  __syncthreads();
  float mu = sa[0] * (1.0f / 2048.0f);
  float var = sb[0] * (1.0f / 2048.0f) - mu * mu;
  float rs = rsqrtf(var + 1e-5f);
  float4 g0 = *(const float4*)(g + t * 8);
  float4 g1 = *(const float4*)(g + t * 8 + 4);
  float4 b0 = *(const float4*)(b + t * 8);
  float4 b1 = *(const float4*)(b + t * 8 + 4);
  float gv[8] = {g0.x, g0.y, g0.z, g0.w, g1.x, g1.y, g1.z, g1.w};
  float bv[8] = {b0.x, b0.y, b0.z, b0.w, b1.x, b1.y, b1.z, b1.w};
  bf16x8 o8;
#pragma unroll
  for (int j = 0; j < 8; ++j) o8[j] = (bf16_t)((a[j] - mu) * rs * gv[j] + bv[j]);
  *(bf16x8*)(h + (size_t)row * 2048 + t * 8) = o8;
}

// ---------------- transpose bf16 [R][C](ldin) -> bf16 [C][R](ldout), batched ----------------
__global__ __launch_bounds__(256) void tb_transpose_bf16(
    const bf16_t* __restrict__ in, int ldin, long long sIn,
    bf16_t* __restrict__ out, int ldout, long long sOut)
{
  __shared__ bf16_t tile[32][40];
  int z = blockIdx.z;
  const bf16_t* src = in + (size_t)z * sIn;
  bf16_t* dst = out + (size_t)z * sOut;
  int c0 = blockIdx.x * 32;
  int r0 = blockIdx.y * 32;
  int t = threadIdx.x;
  int r = t >> 3;
  int c4 = (t & 7) * 4;
  bf16x4 d = *(const bf16x4*)(src + (size_t)(r0 + r) * ldin + c0 + c4);
  *(bf16x4*)&tile[r][c4] = d;
  __syncthreads();
  int c = t >> 3;
  int r4 = (t & 7) * 4;
  bf16x4 o;
  o[0] = tile[r4 + 0][c];
  o[1] = tile[r4 + 1][c];
  o[2] = tile[r4 + 2][c];
  o[3] = tile[r4 + 3][c];
  *(bf16x4*)(dst + (size_t)(c0 + c) * ldout + r0 + r4) = o;
}

// ---------------- Softmax over (p0+p1) rows (bf16 partials in, bf16 out) ----------------
__global__ __launch_bounds__(256) void tb_softmax_add(
    const bf16_t* __restrict__ p, bf16_t* __restrict__ P)
{
  __shared__ float sa[4];
  int row = blockIdx.x;
  int t = threadIdx.x;
  size_t base = ((size_t)(row >> 11) * 2) * 4194304 + (size_t)(row & 2047) * 2048;
  const bf16_t* p0 = p + base;
  const bf16_t* p1 = p0 + 4194304;
  bf16x8 a = *(const bf16x8*)(p0 + t * 8);
  bf16x8 c = *(const bf16x8*)(p1 + t * 8);
  float v[8];
#pragma unroll
  for (int j = 0; j < 8; ++j) v[j] = (float)a[j] + (float)c[j];
  float m = v[0];
#pragma unroll
  for (int j = 1; j < 8; ++j) m = fmaxf(m, v[j]);
#pragma unroll
  for (int o = 32; o; o >>= 1) m = fmaxf(m, __shfl_down(m, o));
  int w = t >> 6, l = t & 63;
  if (l == 0) sa[w] = m;
  __syncthreads();
  if (t == 0) sa[0] = fmaxf(fmaxf(sa[0], sa[1]), fmaxf(sa[2], sa[3]));
  __syncthreads();
  m = sa[0];
  __syncthreads();
  float s = 0.f;
#pragma unroll
  for (int j = 0; j < 8; ++j) { v[j] = expf(v[j] - m); s += v[j]; }
#pragma unroll
  for (int o = 32; o; o >>= 1) s += __shfl_down(s, o);
  if (l == 0) sa[w] = s;
  __syncthreads();
  if (t == 0) sa[0] = sa[0] + sa[1] + sa[2] + sa[3];
  __syncthreads();
  float inv = 1.0f / sa[0];
  bf16x8 o8;
#pragma unroll
  for (int j = 0; j < 8; ++j) o8[j] = (bf16_t)(v[j] * inv);
  *(bf16x8*)(P + (size_t)row * 2048 + t * 8) = o8;
}

// ---------------- host ----------------
extern "C" void kernel_launch(void* const* d_in, const int* in_sizes, int n_in,
                              void* d_out, int out_size, void* d_ws, size_t ws_size,
                              hipStream_t stream) {
  const float* x     = (const float*)d_in[0];
  const float* ln1_g = (const float*)d_in[1];
  const float* ln1_b = (const float*)d_in[2];
  const float* ln2_g = (const float*)d_in[3];
  const float* ln2_b = (const float*)d_in[4];
  const float* qkv_w = (const float*)d_in[5];
  const float* qkv_b = (const float*)d_in[6];
  const float* out_w = (const float*)d_in[7];
  const float* out_b = (const float*)d_in[8];
  const float* w1    = (const float*)d_in[9];
  const float* b1    = (const float*)d_in[10];
  const float* w2    = (const float*)d_in[11];
  const float* b2    = (const float*)d_in[12];
  float* out = (float*)d_out;
  char* ws = (char*)d_ws;

  // ---- workspace layout (bytes) ----
  bf16_t* spb    = (bf16_t*)(ws + 0);           // partials; also qkv_wT early (dead before used)
  bf16_t* qkv_wT = (bf16_t*)(ws + 0);           // [6144][2048] bf16, dead after QKV
  bf16_t* out_wT = (bf16_t*)(ws + 67108864);    // [2048][2048] bf16
  bf16_t* w1T    = (bf16_t*)(ws + 75497472);    // [8192][2048] bf16
  bf16_t* w2T    = (bf16_t*)(ws + 109051904);   // [2048][8192] bf16
  bf16_t* h_bf   = (bf16_t*)(ws + 142606336);   // [4096][2048] bf16
  bf16_t* qkv_bf = (bf16_t*)(ws + 159383552);   // [4096][6144] bf16, dead after scores+Vt
  bf16_t* mid_bf = (bf16_t*)(ws + 159383552);   // [4096][8192] bf16, overlays qkv_bf+attn_bf
  bf16_t* attn_bf= (bf16_t*)(ws + 209715200);   // [2][2048][2048] bf16, dead after PV
  bf16_t* Vt     = (bf16_t*)(ws + 226492416);   // [2][2048][2048] bf16, dead after PV
  bf16_t* ao_bf  = (bf16_t*)(ws + 243269632);   // [4096][2048] bf16, dead after outproj
  float*  x2     = (float*)(ws + 226492416);    // [4096][2048] f32, written at combine_ln (Vt/ao dead)

  const float inv_sqrt_h = 0.022097086912079608f; // 1/sqrt(2048)

  // 1) fused prep: 4 weight transposes + LN1 (one launch)
  tb_prep<<<53248, 256, 0, stream>>>(
      x, ln1_g, ln1_b, h_bf,
      qkv_w, qkv_wT, out_w, out_wT, w1, w1T, w2, w2T);

  // 2) QKV: h_bf @ qkv_w + qkv_b -> qkv_bf  (M=4096, N=6144, K=2048)
  tb_gemm8<EPI_BF16_BIAS, 1><<<dim3(24, 16, 1), 512, 0, stream>>>(
      h_bf, 2048, 0, 0, qkv_wT, 2048, 0, 0, qkv_b, nullptr, qkv_bf, 6144, 0, 2048, 1.0f);

  // 3) V transpose: qkv_bf[z][t][4096+h] -> Vt[z][h][t]
  tb_transpose_bf16<<<dim3(64, 64, 2), 256, 0, stream>>>(
      qkv_bf + 4096, 6144, 2048LL * 6144, Vt, 2048, 2048LL * 2048);

  // 4) scores split-K x2 -> bf16 partials spb[b*2+ks]  (256 blocks)
  tb_gemm8<EPI_BF16, 2><<<dim3(8, 8, 4), 512, 0, stream>>>(
      qkv_bf, 6144, 2048LL * 6144, 1024, qkv_bf + 2048, 6144, 2048LL * 6144, 1024,
      nullptr, nullptr, spb, 2048, 4194304LL, 1024, inv_sqrt_h);

  // 5) softmax over (sp0+sp1) rows -> attn_bf
  tb_softmax_add<<<4096, 256, 0, stream>>>(spb, attn_bf);

  // 6) PV split-K x2 -> bf16 partials spb[b*2+ks]
  tb_gemm8<EPI_BF16, 2><<<dim3(8, 8, 4), 512, 0, stream>>>(
      attn_bf, 2048, 2048LL * 2048, 1024, Vt, 2048, 2048LL * 2048, 1024,
      nullptr, nullptr, spb, 2048, 4194304LL, 1024, 1.0f);

  // 7) PV combine: ao_bf = bf16(sp[2b] + sp[2b+1])
  tb_combine_pv<<<4096, 256, 0, stream>>>(spb, ao_bf);

  // 8) outproj split-K x2 -> bf16 partials spb[ks]  (256 blocks)
  tb_gemm8<EPI_BF16, 2><<<dim3(8, 16, 2), 512, 0, stream>>>(
      ao_bf, 2048, 0, 1024, out_wT, 2048, 0, 1024,
      nullptr, nullptr, spb, 2048, 8388608LL, 1024, 1.0f);

  // 9) fused outproj-combine + LN2: x2 = x + sp0 + sp1 + out_b ; h_bf = LN2(x2)
  tb_combine_ln<<<4096, 256, 0, stream>>>(x, spb, out_b, ln2_g, ln2_b, x2, h_bf);

  // 10) MLP1 + GELU on the EXPERIMENTAL 8-phase kernel (A/B vs champion's 215 us)
  tb_gemm8p<EPI_BF16_BIAS_GELU, 1><<<dim3(32, 16, 1), 512, 0, stream>>>(
      h_bf, 2048, 0, 0, w1T, 2048, 0, 0, b1, nullptr, mid_bf, 8192, 0, 2048, 1.0f);

  // 11) MLP2 split-K x2 -> bf16 partials spb[ks]  (256 blocks)
  tb_gemm8<EPI_BF16, 2><<<dim3(8, 16, 2), 512, 0, stream>>>(
      mid_bf, 8192, 0, 4096, w2T, 8192, 0, 4096,
      nullptr, nullptr, spb, 2048, 8388608LL, 4096, 1.0f);

  // 12) final combine: out = x2 + sp0 + sp1 + b2
  tb_combine_f<<<4096, 256, 0, stream>>>(x2, spb, b2, out);
}

// Round 18
// 644.168 us; speedup vs baseline: 1.0195x; 1.0195x over previous
//
#include <hip/hip_runtime.h>
#include <hip/hip_bf16.h>
#include <math.h>

typedef __bf16 bf16_t;
typedef __bf16 bf16x8 __attribute__((ext_vector_type(8)));
typedef __bf16 bf16x4 __attribute__((ext_vector_type(4)));
typedef float  f32x4  __attribute__((ext_vector_type(4)));

enum { EPI_BF16_BIAS = 0, EPI_F32_SCALE = 1, EPI_BF16 = 2, EPI_F32_BIAS_RES = 3, EPI_BF16_BIAS_GELU = 4 };

__device__ __forceinline__ float gelu_exact(float v) {
  return 0.5f * v * (1.0f + erff(v * 0.7071067811865476f));
}

__device__ __forceinline__ void gld_lds16(const bf16_t* g, bf16_t* l) {
  __builtin_amdgcn_global_load_lds(
      (const __attribute__((address_space(1))) uint32_t*)(uintptr_t)g,
      (__attribute__((address_space(3))) uint32_t*)(uintptr_t)l, 16, 0, 0);
}

#define SB()    __builtin_amdgcn_s_barrier()
#define SCHED() __builtin_amdgcn_sched_barrier(0)
#define VMW0()  asm volatile("s_waitcnt vmcnt(0)" ::: "memory")

// ---------------- GEMM: 256x256 tile, BK=64, 8 waves, 2-phase counted K-loop ----
// (champion, twice-reproduced at ~645.5 us total. Per-CU delivery-bound plateau:
// ~26.8% MfmaUtil @ 1 block/CU — 7 schedule variants all land in 22-27%.)
// C[M][N] = A[M][K] @ B^T (+ epilogue). A:[M][K] bf16 (lda), B:[N][K] bf16 (ldb).
// M,N multiples of 256; K multiple of 64. ZDIV: blockIdx.z -> (batch=z/ZDIV,
// ks=z%ZDIV); A/B offset by ks*kofA/kofB elements (split-K); C at z*strideC.
template<int EPI, int ZDIV>
__global__ __launch_bounds__(512, 2) void tb_gemm8(
    const bf16_t* __restrict__ A, int lda, long long strideA, long long kofA,
    const bf16_t* __restrict__ B, int ldb, long long strideB, long long kofB,
    const float* __restrict__ bias,
    const float* __restrict__ resid,
    void* __restrict__ Cp, int ldc, long long strideC,
    int K, float scale)
{
  __shared__ __align__(16) bf16_t sm[65536];  // 128 KiB: 2 bufs x (A 16384 + B 16384)

  const int tid = threadIdx.x;
  const int lane = tid & 63;
  const int wid = tid >> 6;
  const int wm = wid >> 2;   // 0..1
  const int wn = wid & 3;    // 0..3
  const int lr = lane & 15;
  const int lg = lane >> 4;
  const int z = blockIdx.z;
  const int batch = z / ZDIV;
  const int ks = z % ZDIV;
  const int m0 = blockIdx.y * 256;
  const int n0 = blockIdx.x * 256;

  const bf16_t* Ag = A + (size_t)batch * strideA + (size_t)ks * kofA + (size_t)m0 * lda;
  const bf16_t* Bg = B + (size_t)batch * strideB + (size_t)ks * kofB + (size_t)n0 * ldb;

  const int l3 = lane >> 3;                 // row-within-chunk
  const int sl8 = ((lane & 7) ^ l3) << 3;   // inverse-swizzled source col (elems)

  f32x4 acc[8][4];
#pragma unroll
  for (int i = 0; i < 8; ++i)
#pragma unroll
    for (int j = 0; j < 4; ++j) acc[i][j] = (f32x4){0.f, 0.f, 0.f, 0.f};

  auto stage = [&](int par, int kt) {
    bf16_t* da = sm + (par << 15);
    bf16_t* db = da + 16384;
#pragma unroll
    for (int h = 0; h < 2; ++h)
#pragma unroll
      for (int q = 0; q < 2; ++q) {
        int c = (wid << 1) + q;                 // chunk 0..15
        int row = (h << 7) + (c << 3) + l3;
        gld_lds16(Ag + (size_t)row * lda + kt + sl8, da + (h << 13) + (c << 9) + lane * 8);
        gld_lds16(Bg + (size_t)row * ldb + kt + sl8, db + (h << 13) + (c << 9) + lane * 8);
      }
  };

  // swizzled LDS read: 16B frag at (rowbase+lr, k-slot (ks*4+lg) XOR (lr&7))
#define RD(base, rowbase, kslot) \
  (*(const bf16x8*)((base) + ((rowbase) + lr) * 64 + (((((kslot) << 2) | lg)) ^ (lr & 7)) * 8))

  const int NT = K >> 6;
  stage(0, 0);
  VMW0();
  SB();

  for (int t = 0; t < NT; ++t) {
    SCHED();
    const bf16_t* cura = sm + ((t & 1) << 15);
    const bf16_t* curb = cura + 16384;
    if (t + 1 < NT) stage((t + 1) & 1, (t + 1) << 6);

    bf16x8 bF[4][2], aF[4][2];
#pragma unroll
    for (int jj = 0; jj < 4; ++jj) {
      bF[jj][0] = RD(curb, jj * 64 + wn * 16, 0);
      bF[jj][1] = RD(curb, jj * 64 + wn * 16, 1);
    }
#pragma unroll
    for (int ii = 0; ii < 4; ++ii) {
      aF[ii][0] = RD(cura, ii * 32 + wm * 16, 0);
      aF[ii][1] = RD(cura, ii * 32 + wm * 16, 1);
    }
    __builtin_amdgcn_s_setprio(1);
#pragma unroll
    for (int ii = 0; ii < 4; ++ii)
#pragma unroll
      for (int jj = 0; jj < 4; ++jj)
#pragma unroll
        for (int kk = 0; kk < 2; ++kk)
          acc[ii][jj] = __builtin_amdgcn_mfma_f32_16x16x32_bf16(aF[ii][kk], bF[jj][kk], acc[ii][jj], 0, 0, 0);
    __builtin_amdgcn_s_setprio(0);
#pragma unroll
    for (int ii = 0; ii < 4; ++ii) {
      aF[ii][0] = RD(cura, 128 + ii * 32 + wm * 16, 0);
      aF[ii][1] = RD(cura, 128 + ii * 32 + wm * 16, 1);
    }
    __builtin_amdgcn_s_setprio(1);
#pragma unroll
    for (int ii = 0; ii < 4; ++ii)
#pragma unroll
      for (int jj = 0; jj < 4; ++jj)
#pragma unroll
        for (int kk = 0; kk < 2; ++kk)
          acc[4 + ii][jj] = __builtin_amdgcn_mfma_f32_16x16x32_bf16(aF[ii][kk], bF[jj][kk], acc[4 + ii][jj], 0, 0, 0);
    __builtin_amdgcn_s_setprio(0);

    SCHED();
    if (t + 1 < NT) {
      VMW0();
      SB();
    }
  }
#undef RD

  // ---- epilogue ----
#pragma unroll
  for (int i = 0; i < 8; ++i) {
    const int mr = ((i >> 2) << 7) + ((i & 3) << 5) + (wm << 4);
#pragma unroll
    for (int j = 0; j < 4; ++j) {
      const int nc = j * 64 + (wn << 4);
#pragma unroll
      for (int r = 0; r < 4; ++r) {
        int row = m0 + mr + lg * 4 + r;
        int col = n0 + nc + lr;
        float v = acc[i][j][r] * scale;
        if constexpr (EPI == EPI_BF16_BIAS || EPI == EPI_F32_BIAS_RES || EPI == EPI_BF16_BIAS_GELU)
          v += bias[col];
        if constexpr (EPI == EPI_BF16_BIAS_GELU)
          v = gelu_exact(v);
        if constexpr (EPI == EPI_F32_BIAS_RES)
          v += resid[(size_t)row * ldc + col];
        if constexpr (EPI == EPI_BF16_BIAS || EPI == EPI_BF16 || EPI == EPI_BF16_BIAS_GELU) {
          ((bf16_t*)Cp)[(size_t)z * strideC + (size_t)row * ldc + col] = (bf16_t)v;
        } else {
          ((float*)Cp)[(size_t)z * strideC + (size_t)row * ldc + col] = v;
        }
      }
    }
  }
}

// ---------------- fused prep: 4 weight transposes (f32->bf16 [N][K]) + LN1 ----------------
__device__ __forceinline__ void prep_transpose(
    const float* __restrict__ in, bf16_t* __restrict__ outT, int R, int C,
    int tile_id, float (*tile)[33], int t)
{
  int tx = tile_id % (C / 32);
  int ty = tile_id / (C / 32);
  int c0 = tx * 32;
  int r0 = ty * 32;
  int r = t >> 3;
  int c4 = (t & 7) * 4;
  float4 d = *(const float4*)(in + (size_t)(r0 + r) * C + c0 + c4);
  tile[r][c4 + 0] = d.x; tile[r][c4 + 1] = d.y; tile[r][c4 + 2] = d.z; tile[r][c4 + 3] = d.w;
  __syncthreads();
  int c = t >> 3;
  int r4 = (t & 7) * 4;
  bf16x4 o;
  o[0] = (bf16_t)tile[r4 + 0][c];
  o[1] = (bf16_t)tile[r4 + 1][c];
  o[2] = (bf16_t)tile[r4 + 2][c];
  o[3] = (bf16_t)tile[r4 + 3][c];
  *(bf16x4*)(outT + (size_t)(c0 + c) * R + r0 + r4) = o;
}

__global__ __launch_bounds__(256) void tb_prep(
    const float* __restrict__ x, const float* __restrict__ g, const float* __restrict__ b,
    bf16_t* __restrict__ h,
    const float* __restrict__ qkv_w, bf16_t* __restrict__ qkv_wT,
    const float* __restrict__ out_w, bf16_t* __restrict__ out_wT,
    const float* __restrict__ w1, bf16_t* __restrict__ w1T,
    const float* __restrict__ w2, bf16_t* __restrict__ w2T)
{
  __shared__ float tile[32][33];
  __shared__ float sa[4], sb[4];
  int bid = blockIdx.x;
  int t = threadIdx.x;
  if (bid < 12288) {
    prep_transpose(qkv_w, qkv_wT, 2048, 6144, bid, tile, t);
  } else if (bid < 16384) {
    prep_transpose(out_w, out_wT, 2048, 2048, bid - 12288, tile, t);
  } else if (bid < 32768) {
    prep_transpose(w1, w1T, 2048, 8192, bid - 16384, tile, t);
  } else if (bid < 49152) {
    prep_transpose(w2, w2T, 8192, 2048, bid - 32768, tile, t);
  } else {
    int row = bid - 49152;
    const float* xr = x + (size_t)row * 2048;
    float4 v0 = *(const float4*)(xr + t * 8);
    float4 v1 = *(const float4*)(xr + t * 8 + 4);
    float a[8] = {v0.x, v0.y, v0.z, v0.w, v1.x, v1.y, v1.z, v1.w};
    float s = 0.f, q = 0.f;
#pragma unroll
    for (int j = 0; j < 8; ++j) { s += a[j]; q += a[j] * a[j]; }
#pragma unroll
    for (int o = 32; o; o >>= 1) { s += __shfl_down(s, o); q += __shfl_down(q, o); }
    int w = t >> 6, l = t & 63;
    if (l == 0) { sa[w] = s; sb[w] = q; }
    __syncthreads();
    if (t == 0) {
      sa[0] = sa[0] + sa[1] + sa[2] + sa[3];
      sb[0] = sb[0] + sb[1] + sb[2] + sb[3];
    }
    __syncthreads();
    float mu = sa[0] * (1.0f / 2048.0f);
    float var = sb[0] * (1.0f / 2048.0f) - mu * mu;
    float rs = rsqrtf(var + 1e-5f);
    float4 g0 = *(const float4*)(g + t * 8);
    float4 g1 = *(const float4*)(g + t * 8 + 4);
    float4 b0 = *(const float4*)(b + t * 8);
    float4 b1 = *(const float4*)(b + t * 8 + 4);
    float gv[8] = {g0.x, g0.y, g0.z, g0.w, g1.x, g1.y, g1.z, g1.w};
    float bv[8] = {b0.x, b0.y, b0.z, b0.w, b1.x, b1.y, b1.z, b1.w};
    bf16x8 o8;
#pragma unroll
    for (int j = 0; j < 8; ++j) o8[j] = (bf16_t)((a[j] - mu) * rs * gv[j] + bv[j]);
    *(bf16x8*)(h + (size_t)row * 2048 + t * 8) = o8;
  }
}

// ---------------- final combine: out = x2 + p0 + p1 + bias (p bf16, x2/out f32) ----
__global__ __launch_bounds__(256) void tb_combine_f(
    const float* __restrict__ x2, const bf16_t* __restrict__ p,
    const float* __restrict__ bias, float* __restrict__ out)
{
  size_t o = ((size_t)blockIdx.x * 256 + threadIdx.x) * 8;
  float4 a0 = *(const float4*)(x2 + o);
  float4 a1 = *(const float4*)(x2 + o + 4);
  bf16x8 pa = *(const bf16x8*)(p + o);
  bf16x8 pb = *(const bf16x8*)(p + 8388608 + o);
  size_t c = o & 2047;
  float4 b0 = *(const float4*)(bias + c);
  float4 b1 = *(const float4*)(bias + c + 4);
  float4 r0, r1;
  r0.x = a0.x + (float)pa[0] + (float)pb[0] + b0.x;
  r0.y = a0.y + (float)pa[1] + (float)pb[1] + b0.y;
  r0.z = a0.z + (float)pa[2] + (float)pb[2] + b0.z;
  r0.w = a0.w + (float)pa[3] + (float)pb[3] + b0.w;
  r1.x = a1.x + (float)pa[4] + (float)pb[4] + b1.x;
  r1.y = a1.y + (float)pa[5] + (float)pb[5] + b1.y;
  r1.z = a1.z + (float)pa[6] + (float)pb[6] + b1.z;
  r1.w = a1.w + (float)pa[7] + (float)pb[7] + b1.w;
  *(float4*)(out + o) = r0;
  *(float4*)(out + o + 4) = r1;
}

// ---------------- PV combine: ao = bf16(p[2b] + p[2b+1]), p bf16 [4][2048][2048] ----
__global__ __launch_bounds__(256) void tb_combine_pv(
    const bf16_t* __restrict__ p, bf16_t* __restrict__ ao)
{
  size_t o = ((size_t)blockIdx.x * 256 + threadIdx.x) * 8;   // over 8,388,608 elems
  size_t b = o >> 22;               // batch
  size_t w = o & 4194303;           // within batch
  const bf16_t* p0 = p + (b << 1) * 4194304 + w;
  const bf16_t* p1 = p0 + 4194304;
  bf16x8 a = *(const bf16x8*)p0;
  bf16x8 c = *(const bf16x8*)p1;
  bf16x8 r;
#pragma unroll
  for (int j = 0; j < 8; ++j) r[j] = (bf16_t)((float)a[j] + (float)c[j]);
  *(bf16x8*)(ao + o) = r;
}

// ---------------- fused outproj-combine + LayerNorm2 ----------------
__global__ __launch_bounds__(256) void tb_combine_ln(
    const float* __restrict__ x, const bf16_t* __restrict__ p,
    const float* __restrict__ ob,
    const float* __restrict__ g, const float* __restrict__ b,
    float* __restrict__ x2, bf16_t* __restrict__ h)
{
  __shared__ float sa[4], sb[4];
  int row = blockIdx.x;
  int t = threadIdx.x;
  const float* xr = x + (size_t)row * 2048;
  const bf16_t* p0 = p + (size_t)row * 2048;
  const bf16_t* p1 = p0 + 8388608;
  float4 v0 = *(const float4*)(xr + t * 8);
  float4 v1 = *(const float4*)(xr + t * 8 + 4);
  bf16x8 pa = *(const bf16x8*)(p0 + t * 8);
  bf16x8 pb = *(const bf16x8*)(p1 + t * 8);
  float4 o0 = *(const float4*)(ob + t * 8);
  float4 o1 = *(const float4*)(ob + t * 8 + 4);
  float a[8] = {v0.x, v0.y, v0.z, v0.w, v1.x, v1.y, v1.z, v1.w};
  float ov[8] = {o0.x, o0.y, o0.z, o0.w, o1.x, o1.y, o1.z, o1.w};
  float s = 0.f, q = 0.f;
#pragma unroll
  for (int j = 0; j < 8; ++j) {
    a[j] += (float)pa[j] + (float)pb[j] + ov[j];
    s += a[j]; q += a[j] * a[j];
  }
  float4 w0 = {a[0], a[1], a[2], a[3]};
  float4 w1 = {a[4], a[5], a[6], a[7]};
  *(float4*)(x2 + (size_t)row * 2048 + t * 8) = w0;
  *(float4*)(x2 + (size_t)row * 2048 + t * 8 + 4) = w1;
#pragma unroll
  for (int o = 32; o; o >>= 1) { s += __shfl_down(s, o); q += __shfl_down(q, o); }
  int w = t >> 6, l = t & 63;
  if (l == 0) { sa[w] = s; sb[w] = q; }
  __syncthreads();
  if (t == 0) {
    sa[0] = sa[0] + sa[1] + sa[2] + sa[3];
    sb[0] = sb[0] + sb[1] + sb[2] + sb[3];
  }
  __syncthreads();
  float mu = sa[0] * (1.0f / 2048.0f);
  float var = sb[0] * (1.0f / 2048.0f) - mu * mu;
  float rs = rsqrtf(var + 1e-5f);
  float4 g0 = *(const float4*)(g + t * 8);
  float4 g1 = *(const float4*)(g + t * 8 + 4);
  float4 b0 = *(const float4*)(b + t * 8);
  float4 b1 = *(const float4*)(b + t * 8 + 4);
  float gv[8] = {g0.x, g0.y, g0.z, g0.w, g1.x, g1.y, g1.z, g1.w};
  float bv[8] = {b0.x, b0.y, b0.z, b0.w, b1.x, b1.y, b1.z, b1.w};
  bf16x8 o8;
#pragma unroll
  for (int j = 0; j < 8; ++j) o8[j] = (bf16_t)((a[j] - mu) * rs * gv[j] + bv[j]);
  *(bf16x8*)(h + (size_t)row * 2048 + t * 8) = o8;
}

// ---------------- transpose bf16 [R][C](ldin) -> bf16 [C][R](ldout), batched ----------------
__global__ __launch_bounds__(256) void tb_transpose_bf16(
    const bf16_t* __restrict__ in, int ldin, long long sIn,
    bf16_t* __restrict__ out, int ldout, long long sOut)
{
  __shared__ bf16_t tile[32][40];
  int z = blockIdx.z;
  const bf16_t* src = in + (size_t)z * sIn;
  bf16_t* dst = out + (size_t)z * sOut;
  int c0 = blockIdx.x * 32;
  int r0 = blockIdx.y * 32;
  int t = threadIdx.x;
  int r = t >> 3;
  int c4 = (t & 7) * 4;
  bf16x4 d = *(const bf16x4*)(src + (size_t)(r0 + r) * ldin + c0 + c4);
  *(bf16x4*)&tile[r][c4] = d;
  __syncthreads();
  int c = t >> 3;
  int r4 = (t & 7) * 4;
  bf16x4 o;
  o[0] = tile[r4 + 0][c];
  o[1] = tile[r4 + 1][c];
  o[2] = tile[r4 + 2][c];
  o[3] = tile[r4 + 3][c];
  *(bf16x4*)(dst + (size_t)(c0 + c) * ldout + r0 + r4) = o;
}

// ---------------- Softmax over (p0+p1) rows (bf16 partials in, bf16 out) ----------------
__global__ __launch_bounds__(256) void tb_softmax_add(
    const bf16_t* __restrict__ p, bf16_t* __restrict__ P)
{
  __shared__ float sa[4];
  int row = blockIdx.x;
  int t = threadIdx.x;
  size_t base = ((size_t)(row >> 11) * 2) * 4194304 + (size_t)(row & 2047) * 2048;
  const bf16_t* p0 = p + base;
  const bf16_t* p1 = p0 + 4194304;
  bf16x8 a = *(const bf16x8*)(p0 + t * 8);
  bf16x8 c = *(const bf16x8*)(p1 + t * 8);
  float v[8];
#pragma unroll
  for (int j = 0; j < 8; ++j) v[j] = (float)a[j] + (float)c[j];
  float m = v[0];
#pragma unroll
  for (int j = 1; j < 8; ++j) m = fmaxf(m, v[j]);
#pragma unroll
  for (int o = 32; o; o >>= 1) m = fmaxf(m, __shfl_down(m, o));
  int w = t >> 6, l = t & 63;
  if (l == 0) sa[w] = m;
  __syncthreads();
  if (t == 0) sa[0] = fmaxf(fmaxf(sa[0], sa[1]), fmaxf(sa[2], sa[3]));
  __syncthreads();
  m = sa[0];
  __syncthreads();
  float s = 0.f;
#pragma unroll
  for (int j = 0; j < 8; ++j) { v[j] = expf(v[j] - m); s += v[j]; }
#pragma unroll
  for (int o = 32; o; o >>= 1) s += __shfl_down(s, o);
  if (l == 0) sa[w] = s;
  __syncthreads();
  if (t == 0) sa[0] = sa[0] + sa[1] + sa[2] + sa[3];
  __syncthreads();
  float inv = 1.0f / sa[0];
  bf16x8 o8;
#pragma unroll
  for (int j = 0; j < 8; ++j) o8[j] = (bf16_t)(v[j] * inv);
  *(bf16x8*)(P + (size_t)row * 2048 + t * 8) = o8;
}

// ---------------- host ----------------
extern "C" void kernel_launch(void* const* d_in, const int* in_sizes, int n_in,
                              void* d_out, int out_size, void* d_ws, size_t ws_size,
                              hipStream_t stream) {
  const float* x     = (const float*)d_in[0];
  const float* ln1_g = (const float*)d_in[1];
  const float* ln1_b = (const float*)d_in[2];
  const float* ln2_g = (const float*)d_in[3];
  const float* ln2_b = (const float*)d_in[4];
  const float* qkv_w = (const float*)d_in[5];
  const float* qkv_b = (const float*)d_in[6];
  const float* out_w = (const float*)d_in[7];
  const float* out_b = (const float*)d_in[8];
  const float* w1    = (const float*)d_in[9];
  const float* b1    = (const float*)d_in[10];
  const float* w2    = (const float*)d_in[11];
  const float* b2    = (const float*)d_in[12];
  float* out = (float*)d_out;
  char* ws = (char*)d_ws;

  // ---- workspace layout (bytes) ----
  bf16_t* spb    = (bf16_t*)(ws + 0);           // partials; also qkv_wT early (dead before used)
  bf16_t* qkv_wT = (bf16_t*)(ws + 0);           // [6144][2048] bf16, dead after QKV
  bf16_t* out_wT = (bf16_t*)(ws + 67108864);    // [2048][2048] bf16
  bf16_t* w1T    = (bf16_t*)(ws + 75497472);    // [8192][2048] bf16
  bf16_t* w2T    = (bf16_t*)(ws + 109051904);   // [2048][8192] bf16
  bf16_t* h_bf   = (bf16_t*)(ws + 142606336);   // [4096][2048] bf16
  bf16_t* qkv_bf = (bf16_t*)(ws + 159383552);   // [4096][6144] bf16, dead after scores+Vt
  bf16_t* mid_bf = (bf16_t*)(ws + 159383552);   // [4096][8192] bf16, overlays qkv_bf+attn_bf
  bf16_t* attn_bf= (bf16_t*)(ws + 209715200);   // [2][2048][2048] bf16, dead after PV
  bf16_t* Vt     = (bf16_t*)(ws + 226492416);   // [2][2048][2048] bf16, dead after PV
  bf16_t* ao_bf  = (bf16_t*)(ws + 243269632);   // [4096][2048] bf16, dead after outproj
  float*  x2     = (float*)(ws + 226492416);    // [4096][2048] f32, written at combine_ln (Vt/ao dead)

  const float inv_sqrt_h = 0.022097086912079608f; // 1/sqrt(2048)

  // 1) fused prep: 4 weight transposes + LN1 (one launch)
  tb_prep<<<53248, 256, 0, stream>>>(
      x, ln1_g, ln1_b, h_bf,
      qkv_w, qkv_wT, out_w, out_wT, w1, w1T, w2, w2T);

  // 2) QKV: h_bf @ qkv_w + qkv_b -> qkv_bf  (M=4096, N=6144, K=2048)
  tb_gemm8<EPI_BF16_BIAS, 1><<<dim3(24, 16, 1), 512, 0, stream>>>(
      h_bf, 2048, 0, 0, qkv_wT, 2048, 0, 0, qkv_b, nullptr, qkv_bf, 6144, 0, 2048, 1.0f);

  // 3) V transpose: qkv_bf[z][t][4096+h] -> Vt[z][h][t]
  tb_transpose_bf16<<<dim3(64, 64, 2), 256, 0, stream>>>(
      qkv_bf + 4096, 6144, 2048LL * 6144, Vt, 2048, 2048LL * 2048);

  // 4) scores split-K x2 -> bf16 partials spb[b*2+ks]  (256 blocks)
  tb_gemm8<EPI_BF16, 2><<<dim3(8, 8, 4), 512, 0, stream>>>(
      qkv_bf, 6144, 2048LL * 6144, 1024, qkv_bf + 2048, 6144, 2048LL * 6144, 1024,
      nullptr, nullptr, spb, 2048, 4194304LL, 1024, inv_sqrt_h);

  // 5) softmax over (sp0+sp1) rows -> attn_bf
  tb_softmax_add<<<4096, 256, 0, stream>>>(spb, attn_bf);

  // 6) PV split-K x2 -> bf16 partials spb[b*2+ks]
  tb_gemm8<EPI_BF16, 2><<<dim3(8, 8, 4), 512, 0, stream>>>(
      attn_bf, 2048, 2048LL * 2048, 1024, Vt, 2048, 2048LL * 2048, 1024,
      nullptr, nullptr, spb, 2048, 4194304LL, 1024, 1.0f);

  // 7) PV combine: ao_bf = bf16(sp[2b] + sp[2b+1])
  tb_combine_pv<<<4096, 256, 0, stream>>>(spb, ao_bf);

  // 8) outproj split-K x2 -> bf16 partials spb[ks]  (256 blocks)
  tb_gemm8<EPI_BF16, 2><<<dim3(8, 16, 2), 512, 0, stream>>>(
      ao_bf, 2048, 0, 1024, out_wT, 2048, 0, 1024,
      nullptr, nullptr, spb, 2048, 8388608LL, 1024, 1.0f);

  // 9) fused outproj-combine + LN2: x2 = x + sp0 + sp1 + out_b ; h_bf = LN2(x2)
  tb_combine_ln<<<4096, 256, 0, stream>>>(x, spb, out_b, ln2_g, ln2_b, x2, h_bf);

  // 10) MLP1 + GELU: mid_bf = gelu(h_bf @ w1 + b1)  (M=4096, N=8192, K=2048, 512 blocks)
  tb_gemm8<EPI_BF16_BIAS_GELU, 1><<<dim3(32, 16, 1), 512, 0, stream>>>(
      h_bf, 2048, 0, 0, w1T, 2048, 0, 0, b1, nullptr, mid_bf, 8192, 0, 2048, 1.0f);

  // 11) MLP2 split-K x2 -> bf16 partials spb[ks]  (256 blocks)
  tb_gemm8<EPI_BF16, 2><<<dim3(8, 16, 2), 512, 0, stream>>>(
      mid_bf, 8192, 0, 4096, w2T, 8192, 0, 4096,
      nullptr, nullptr, spb, 2048, 8388608LL, 4096, 1.0f);

  // 12) final combine: out = x2 + sp0 + sp1 + b2
  tb_combine_f<<<4096, 256, 0, stream>>>(x2, spb, b2, out);
}